// Round 13
// baseline (46.132 us; speedup 1.0000x reference)
//
#include <hip/hip_runtime.h>
#include <math.h>

// ParametricEQ: 5-section cascaded biquad over (32, 131072).
// 10-state linear recurrence z' = A z + b x (A block-lower-triangular).
// Wait-free 3-kernel pipeline. ALL KS-scan and reconstruction steps are
// BRANCHLESS (uniform control flow + per-lane selects) so the wave-uniform
// P-matrix loads scalarize to s_load / SGPR operands and hoist freely.
//   K1  setup : RBJ coeffs (fp64) + P_m = A^(16*2^m), m=0..12.
//   K2a pass1 : skewed zero-state cascade; branchless in-wave KS (P0..P5);
//               store per-chunk exclusive prefix es; lane63 -> wave total.
//   K2b pass2 : branchless in-wave scan of 128 wave totals (P6..P12) -> seed;
//               branchless F = A^(16*lw)*seed + es; skewed final cascade;
//               y through padded LDS -> coalesced writes.

#define NB 32
#define LCH 16
#define T_LEN 131072
#define CPB 256                 // chunks per block (K2a/K2b)
#define BPB 32                  // blocks per batch
#define CCH 8192                // chunks per batch
#define WPB 128                 // waves per batch
#define NPOW 13

__constant__ double c_lo[15] = {-12.0,   20.0, 0.1,
                                -12.0,   20.0, 0.1,
                                -12.0,  200.0, 0.1,
                                -12.0, 2000.0, 0.1,
                                -12.0, 4000.0, 0.1};
__constant__ double c_hi[15] = { 12.0,  2000.0, 10.0,
                                 12.0,   200.0, 10.0,
                                 12.0,  2000.0, 10.0,
                                 12.0, 12000.0, 10.0,
                                 12.0, 16000.0, 10.0};

// ---------------- K1: coeffs + cascade matrix powers -----------------------
__global__ __launch_bounds__(128)
void eq_setup(const float* __restrict__ cp, float* __restrict__ sos_out,
              float* __restrict__ powers)
{
    int b = blockIdx.x;
    int t = threadIdx.x;
    __shared__ float  sc[5][5];
    __shared__ double Abuf[2][10][10];

    if (t < 5) {
        int k = t;
        double p[3];
#pragma unroll
        for (int j = 0; j < 3; ++j) {
            int i = k * 3 + j;
            double pv = (double)cp[b * 15 + i];
            p[j] = c_lo[i] + pv * (c_hi[i] - c_lo[i]);
        }
        double A     = exp(p[0] * (M_LN10 / 40.0));
        double w0    = 2.0 * M_PI * p[1] / 44100.0;
        double alpha = sin(w0) / (2.0 * p[2]);
        double cw    = cos(w0);
        double sA    = sqrt(A);
        double b0, b1, b2, a0, a1, a2;
        if (k == 0) {            // low shelf
            b0 =     A * ((A + 1) - (A - 1) * cw + 2 * sA * alpha);
            b1 = 2 * A * ((A - 1) - (A + 1) * cw);
            b2 =     A * ((A + 1) - (A - 1) * cw - 2 * sA * alpha);
            a0 =          (A + 1) + (A - 1) * cw + 2 * sA * alpha;
            a1 =    -2 * ((A - 1) + (A + 1) * cw);
            a2 =          (A + 1) + (A - 1) * cw - 2 * sA * alpha;
        } else if (k == 4) {     // high shelf
            b0 =     A * ((A + 1) + (A - 1) * cw + 2 * sA * alpha);
            b1 = -2 * A * ((A - 1) + (A + 1) * cw);
            b2 =     A * ((A + 1) + (A - 1) * cw - 2 * sA * alpha);
            a0 =          (A + 1) - (A - 1) * cw + 2 * sA * alpha;
            a1 =     2 * ((A - 1) - (A + 1) * cw);
            a2 =          (A + 1) - (A - 1) * cw - 2 * sA * alpha;
        } else {                 // peaking
            b0 = 1.0 + alpha * A;
            b1 = -2.0 * cw;
            b2 = 1.0 - alpha * A;
            a0 = 1.0 + alpha / A;
            a1 = -2.0 * cw;
            a2 = 1.0 - alpha / A;
        }
        double inv = 1.0 / a0;
        float fb0 = (float)(b0 * inv), fb1 = (float)(b1 * inv), fb2 = (float)(b2 * inv);
        float fa1 = (float)(a1 * inv), fa2 = (float)(a2 * inv);
        float* o = sos_out + (size_t)(b * 5 + k) * 6;
        o[0] = fb0; o[1] = fb1; o[2] = fb2; o[3] = 1.0f; o[4] = fa1; o[5] = fa2;
        sc[k][0] = fb0; sc[k][1] = fb1; sc[k][2] = fb2; sc[k][3] = fa1; sc[k][4] = fa2;
    }
    __syncthreads();

    // A (10x10): column i = one-sample cascade update of basis e_i with x=0.
    if (t < 10) {
        double z[10];
#pragma unroll
        for (int i = 0; i < 10; ++i) z[i] = 0.0;
        z[t] = 1.0;
        double s = 0.0;
        double zn[10];
#pragma unroll
        for (int k = 0; k < 5; ++k) {
            double b0 = sc[k][0], b1 = sc[k][1], b2 = sc[k][2];
            double a1 = sc[k][3], a2 = sc[k][4];
            double y = b0 * s + z[2 * k];
            zn[2 * k]     = b1 * s - a1 * y + z[2 * k + 1];
            zn[2 * k + 1] = b2 * s - a2 * y;
            s = y;
        }
#pragma unroll
        for (int r = 0; r < 10; ++r) Abuf[0][r][t] = zn[r];
    }
    __syncthreads();

    int r = t / 10, cc = t % 10;
    int cur = 0;
    for (int sq = 0; sq < 16; ++sq) {
        double acc = 0.0;
        if (t < 100) {
#pragma unroll
            for (int j = 0; j < 10; ++j) acc += Abuf[cur][r][j] * Abuf[cur][j][cc];
        }
        __syncthreads();
        if (t < 100) Abuf[cur ^ 1][r][cc] = acc;
        __syncthreads();
        cur ^= 1;
        if (sq >= 3 && t < 100) {
            int m = sq - 3;   // sq=3 -> A^16 = P_0 ... sq=15 -> A^65536 = P_12
            powers[((size_t)b * NPOW + m) * 100 + t] = (float)Abuf[cur][r][cc];
        }
    }
}

// ---- triangular affine into SEPARATE output: vout = P*u (+ vin if ACC).
// P is a GLOBAL 10x10 matrix at a wave-uniform address in uniform control
// flow -> s_load / SGPR operands. Row rr uses cols 0..(rr|1). Two
// accumulator chains per row halve the dependent-FMA depth. ----
template<bool ACC>
__device__ __forceinline__ void affineTo(const float* __restrict__ P,
                                         const float u[10],
                                         const float vin[10], float vout[10])
{
#pragma unroll
    for (int rr = 0; rr < 10; ++rr) {
        const float* rp = P + rr * 10;
        float a = ACC ? vin[rr] : 0.0f;
        float bacc = 0.0f;
#pragma unroll
        for (int c = 0; c <= (rr | 1); c += 2) {
            a = fmaf(rp[c], u[c], a);
            bacc = fmaf(rp[c + 1], u[c + 1], bacc);   // c+1 <= rr|1 always (odd)
        }
        vout[rr] = a + bacc;
    }
}

// ---- one biquad section update (bit-identical to original ordering) ----
__device__ __forceinline__ float secstep(int k, float s,
                                         const float cb0[5], const float cb1[5],
                                         const float cb2[5], const float ca1[5],
                                         const float ca2[5], float z1[5], float z2[5])
{
    float yk = fmaf(cb0[k], s, z1[k]);
    float u  = fmaf(cb1[k], s, z2[k]);
    z1[k] = fmaf(-ca1[k], yk, u);
    z2[k] = fmaf(-ca2[k], yk, cb2[k] * s);
    return yk;
}

// ---------------- K2a: pass1 — per-chunk exclusive prefixes + wave totals ---
__global__ __launch_bounds__(256, 4)
void eq_pass1(const float* __restrict__ x, const float* __restrict__ sos,
              const float* __restrict__ powers, float* __restrict__ es_g,
              float* __restrict__ wt)
{
    int blk = blockIdx.x;
    int b = blk >> 5, sp = blk & (BPB - 1);
    int tid = threadIdx.x;
    int w = tid >> 6, lw = tid & 63;

    const float* s5 = sos + (size_t)(b * 5) * 6;
    float cb0[5], cb1[5], cb2[5], ca1[5], ca2[5];
#pragma unroll
    for (int k = 0; k < 5; ++k) {
        cb0[k] = s5[k * 6 + 0]; cb1[k] = s5[k * 6 + 1]; cb2[k] = s5[k * 6 + 2];
        ca1[k] = s5[k * 6 + 4]; ca2[k] = s5[k * 6 + 5];
    }

    int c = sp * CPB + tid;
    const float* xp = x + (size_t)b * T_LEN + (size_t)c * LCH;
    float xr[LCH];
#pragma unroll
    for (int t0 = 0; t0 < LCH; t0 += 4) {
        float4 xv = *reinterpret_cast<const float4*>(xp + t0);
        xr[t0] = xv.x; xr[t0 + 1] = xv.y; xr[t0 + 2] = xv.z; xr[t0 + 3] = xv.w;
    }

    // ---- skewed zero-state cascade ----
    float z1[5] = {0, 0, 0, 0, 0}, z2[5] = {0, 0, 0, 0, 0};
    {
        float c0 = 0.f, c1 = 0.f, c2 = 0.f, c3 = 0.f;
#pragma unroll
        for (int t = 0; t < LCH + 4; ++t) {
            float o0 = 0.f, o1 = 0.f, o2 = 0.f, o3 = 0.f;
            if (t < LCH)              o0 = secstep(0, xr[t], cb0, cb1, cb2, ca1, ca2, z1, z2);
            if (t >= 1 && t < LCH + 1) o1 = secstep(1, c0, cb0, cb1, cb2, ca1, ca2, z1, z2);
            if (t >= 2 && t < LCH + 2) o2 = secstep(2, c1, cb0, cb1, cb2, ca1, ca2, z1, z2);
            if (t >= 3 && t < LCH + 3) o3 = secstep(3, c2, cb0, cb1, cb2, ca1, ca2, z1, z2);
            if (t >= 4)               (void)secstep(4, c3, cb0, cb1, cb2, ca1, ca2, z1, z2);
            if (t < LCH)              c0 = o0;
            if (t >= 1 && t < LCH + 1) c1 = o1;
            if (t >= 2 && t < LCH + 2) c2 = o2;
            if (t >= 3 && t < LCH + 3) c3 = o3;
        }
    }
    float sv[10];
#pragma unroll
    for (int k = 0; k < 5; ++k) { sv[2 * k] = z1[k]; sv[2 * k + 1] = z2[k]; }

    // ---- branchless in-wave KS scan over 64 chunks (P_0..P_5) ----
    const float* Pb = powers + (size_t)b * NPOW * 100;
#pragma unroll
    for (int j = 0; j < 6; ++j) {
        const float* P = Pb + j * 100;
        float u[10], ns[10];
#pragma unroll
        for (int i = 0; i < 10; ++i) u[i] = __shfl_up(sv[i], 1 << j);
        affineTo<true>(P, u, sv, ns);
        bool take = lw >= (1 << j);
#pragma unroll
        for (int i = 0; i < 10; ++i) sv[i] = take ? ns[i] : sv[i];
    }

    // exclusive in-wave prefix -> global (i-major, coalesced)
    float es[10];
#pragma unroll
    for (int i = 0; i < 10; ++i) {
        float e = __shfl_up(sv[i], 1);
        es[i] = (lw == 0) ? 0.0f : e;
    }
    float* ep = es_g + (size_t)b * 10 * CCH + c;
#pragma unroll
    for (int i = 0; i < 10; ++i) ep[(size_t)i * CCH] = es[i];

    if (lw == 63) {
        int wid = sp * 4 + w;
        float* wp = wt + (size_t)(b * WPB + wid) * 10;
#pragma unroll
        for (int i = 0; i < 10; ++i) wp[i] = sv[i];
    }
}

// ---------------- K2b: pass2 — fused scan + exact states + output ----------
__global__ __launch_bounds__(256, 4)
void eq_pass2(const float* __restrict__ x, const float* __restrict__ sos,
              const float* __restrict__ powers, const float* __restrict__ wt,
              const float* __restrict__ es_g, float* __restrict__ y)
{
    int blk = blockIdx.x;
    int b = blk >> 5, sp = blk & (BPB - 1);
    int tid = threadIdx.x;
    int w = tid >> 6, lw = tid & 63;

    __shared__ float ys[CPB * 17];          // 17.4 KB, stride-17 padded

    const float* Pb = powers + (size_t)b * NPOW * 100;
    int wid = sp * 4 + w;                   // this wave's global wave index

    // ---- branchless in-wave scan over this batch's 128 wave totals ----
    const float* wp = wt + (size_t)(b * WPB + 2 * lw) * 10;
    float t0[10], t1[10];
#pragma unroll
    for (int i = 0; i < 10; ++i) { t0[i] = wp[i]; t1[i] = wp[10 + i]; }

    float tau[10];
    affineTo<true>(Pb + 6 * 100, t0, t1, tau);   // pair total (2048 samples)

#pragma unroll
    for (int j = 0; j < 6; ++j) {           // KS over 64 pairs, P_(7+j)
        const float* P = Pb + (7 + j) * 100;
        float u[10], ns[10];
#pragma unroll
        for (int i = 0; i < 10; ++i) u[i] = __shfl_up(tau[i], 1 << j);
        affineTo<true>(P, u, tau, ns);
        bool take = lw >= (1 << j);
#pragma unroll
        for (int i = 0; i < 10; ++i) tau[i] = take ? ns[i] : tau[i];
    }

    float e[10];                            // entering state of wave 2lw
#pragma unroll
    for (int i = 0; i < 10; ++i) {
        float ev = __shfl_up(tau[i], 1);
        e[i] = (lw == 0) ? 0.0f : ev;
    }
    float s1[10];                           // entering state of wave 2lw+1
    affineTo<true>(Pb + 6 * 100, e, t0, s1);

    // this wave's seed: lane (wid>>1)'s e (wid even) or s1 (wid odd)
    float F[10];
#pragma unroll
    for (int i = 0; i < 10; ++i)
        F[i] = __shfl((wid & 1) ? s1[i] : e[i], wid >> 1);

    // ---- x load ----
    int c = sp * CPB + tid;
    const float* xp = x + (size_t)b * T_LEN + (size_t)c * LCH;
    float xr[LCH];
#pragma unroll
    for (int t2 = 0; t2 < LCH; t2 += 4) {
        float4 xv = *reinterpret_cast<const float4*>(xp + t2);
        xr[t2] = xv.x; xr[t2 + 1] = xv.y; xr[t2 + 2] = xv.z; xr[t2 + 3] = xv.w;
    }

    // ---- branchless F = A^(16*lw) * seed (powers commute) ----
#pragma unroll
    for (int m = 0; m < 6; ++m) {
        float ns[10];
        affineTo<false>(Pb + m * 100, F, F, ns);
        bool take = (lw >> m) & 1;
#pragma unroll
        for (int i = 0; i < 10; ++i) F[i] = take ? ns[i] : F[i];
    }

    const float* s5 = sos + (size_t)(b * 5) * 6;
    float cb0[5], cb1[5], cb2[5], ca1[5], ca2[5];
#pragma unroll
    for (int k = 0; k < 5; ++k) {
        cb0[k] = s5[k * 6 + 0]; cb1[k] = s5[k * 6 + 1]; cb2[k] = s5[k * 6 + 2];
        ca1[k] = s5[k * 6 + 4]; ca2[k] = s5[k * 6 + 5];
    }

    const float* ep = es_g + (size_t)b * 10 * CCH + c;
    float z1[5], z2[5];
#pragma unroll
    for (int k = 0; k < 5; ++k) {
        z1[k] = F[2 * k]     + ep[(size_t)(2 * k) * CCH];
        z2[k] = F[2 * k + 1] + ep[(size_t)(2 * k + 1) * CCH];
    }

    // ---- skewed final cascade -> LDS (padded stride 17) ----
    float* yl = ys + tid * 17;
    {
        float c0 = 0.f, c1 = 0.f, c2 = 0.f, c3 = 0.f;
#pragma unroll
        for (int t = 0; t < LCH + 4; ++t) {
            float o0 = 0.f, o1 = 0.f, o2 = 0.f, o3 = 0.f, o4 = 0.f;
            if (t < LCH)              o0 = secstep(0, xr[t], cb0, cb1, cb2, ca1, ca2, z1, z2);
            if (t >= 1 && t < LCH + 1) o1 = secstep(1, c0, cb0, cb1, cb2, ca1, ca2, z1, z2);
            if (t >= 2 && t < LCH + 2) o2 = secstep(2, c1, cb0, cb1, cb2, ca1, ca2, z1, z2);
            if (t >= 3 && t < LCH + 3) o3 = secstep(3, c2, cb0, cb1, cb2, ca1, ca2, z1, z2);
            if (t >= 4)               o4 = secstep(4, c3, cb0, cb1, cb2, ca1, ca2, z1, z2);
            if (t < LCH)              c0 = o0;
            if (t >= 1 && t < LCH + 1) c1 = o1;
            if (t >= 2 && t < LCH + 2) c2 = o2;
            if (t >= 3 && t < LCH + 3) c3 = o3;
            if (t >= 4)               yl[t - 4] = o4;
        }
    }
    __syncthreads();

    // ---- coalesced copy-out: 256 threads x 4 float4 = 4096 samples ----
    float* yg = y + (size_t)b * T_LEN + (size_t)sp * (CPB * LCH);
#pragma unroll
    for (int it = 0; it < (CPB * LCH) / (256 * 4); ++it) {
        int i = (tid + it * 256) * 4;
        int p = (i >> 4) * 17 + (i & 15);
        *reinterpret_cast<float4*>(yg + i) =
            make_float4(ys[p], ys[p + 1], ys[p + 2], ys[p + 3]);
    }
}

extern "C" void kernel_launch(void* const* d_in, const int* in_sizes, int n_in,
                              void* d_out, int out_size, void* d_ws, size_t ws_size,
                              hipStream_t stream)
{
    const float* x  = (const float*)d_in[0];
    const float* cp = (const float*)d_in[1];
    float* out = (float*)d_out;
    float* sos = out + (size_t)NB * T_LEN;          // sos tail of d_out

    float* powers = (float*)d_ws;                        // NB*NPOW*100
    float* wt     = powers + (size_t)NB * NPOW * 100;    // NB*WPB*10
    float* es_g   = wt + (size_t)NB * WPB * 10;          // NB*10*CCH

    eq_setup<<<dim3(NB), dim3(128), 0, stream>>>(cp, sos, powers);
    eq_pass1<<<dim3(NB * BPB), dim3(256), 0, stream>>>(x, sos, powers, es_g, wt);
    eq_pass2<<<dim3(NB * BPB), dim3(256), 0, stream>>>(x, sos, powers, wt, es_g, out);
}

// Round 14
// 45.051 us; speedup vs baseline: 1.0240x; 1.0240x over previous
//
#include <hip/hip_runtime.h>
#include <math.h>

// ParametricEQ: 5-section cascaded biquad over (32, 131072).
// 10-state linear recurrence z' = A z + b x (A block-lower-triangular).
// Wait-free 3-kernel pipeline; P matrices via wave-uniform global loads
// (s_load / SGPR operands). R14: launch_bounds (256,2) — lift the 128-VGPR
// cap that (256,4) imposed since R8 (suspected scratch spills in passes).
//   K1  setup : RBJ coeffs (fp64) + P_m = A^(16*2^m), m=0..12.
//   K2a pass1 : zero-state cascade; in-wave KS (P0..P5);
//               store per-chunk exclusive prefix es; lane63 -> wave total.
//   K2b pass2 : in-wave redundant scan of 128 wave totals (P6..P12) -> seed;
//               F = A^(16*lw)*seed + es -> exact state; final cascade;
//               y through padded LDS -> coalesced writes.

#define NB 32
#define LCH 16
#define T_LEN 131072
#define CPB 256                 // chunks per block (K2a/K2b)
#define BPB 32                  // blocks per batch
#define CCH 8192                // chunks per batch
#define WPB 128                 // waves per batch
#define NPOW 13

__constant__ double c_lo[15] = {-12.0,   20.0, 0.1,
                                -12.0,   20.0, 0.1,
                                -12.0,  200.0, 0.1,
                                -12.0, 2000.0, 0.1,
                                -12.0, 4000.0, 0.1};
__constant__ double c_hi[15] = { 12.0,  2000.0, 10.0,
                                 12.0,   200.0, 10.0,
                                 12.0,  2000.0, 10.0,
                                 12.0, 12000.0, 10.0,
                                 12.0, 16000.0, 10.0};

// ---------------- K1: coeffs + cascade matrix powers -----------------------
__global__ __launch_bounds__(128)
void eq_setup(const float* __restrict__ cp, float* __restrict__ sos_out,
              float* __restrict__ powers)
{
    int b = blockIdx.x;
    int t = threadIdx.x;
    __shared__ float  sc[5][5];
    __shared__ double Abuf[2][10][10];

    if (t < 5) {
        int k = t;
        double p[3];
#pragma unroll
        for (int j = 0; j < 3; ++j) {
            int i = k * 3 + j;
            double pv = (double)cp[b * 15 + i];
            p[j] = c_lo[i] + pv * (c_hi[i] - c_lo[i]);
        }
        double A     = exp(p[0] * (M_LN10 / 40.0));
        double w0    = 2.0 * M_PI * p[1] / 44100.0;
        double alpha = sin(w0) / (2.0 * p[2]);
        double cw    = cos(w0);
        double sA    = sqrt(A);
        double b0, b1, b2, a0, a1, a2;
        if (k == 0) {            // low shelf
            b0 =     A * ((A + 1) - (A - 1) * cw + 2 * sA * alpha);
            b1 = 2 * A * ((A - 1) - (A + 1) * cw);
            b2 =     A * ((A + 1) - (A - 1) * cw - 2 * sA * alpha);
            a0 =          (A + 1) + (A - 1) * cw + 2 * sA * alpha;
            a1 =    -2 * ((A - 1) + (A + 1) * cw);
            a2 =          (A + 1) + (A - 1) * cw - 2 * sA * alpha;
        } else if (k == 4) {     // high shelf
            b0 =     A * ((A + 1) + (A - 1) * cw + 2 * sA * alpha);
            b1 = -2 * A * ((A - 1) + (A + 1) * cw);
            b2 =     A * ((A + 1) + (A - 1) * cw - 2 * sA * alpha);
            a0 =          (A + 1) - (A - 1) * cw + 2 * sA * alpha;
            a1 =     2 * ((A - 1) - (A + 1) * cw);
            a2 =          (A + 1) - (A - 1) * cw - 2 * sA * alpha;
        } else {                 // peaking
            b0 = 1.0 + alpha * A;
            b1 = -2.0 * cw;
            b2 = 1.0 - alpha * A;
            a0 = 1.0 + alpha / A;
            a1 = -2.0 * cw;
            a2 = 1.0 - alpha / A;
        }
        double inv = 1.0 / a0;
        float fb0 = (float)(b0 * inv), fb1 = (float)(b1 * inv), fb2 = (float)(b2 * inv);
        float fa1 = (float)(a1 * inv), fa2 = (float)(a2 * inv);
        float* o = sos_out + (size_t)(b * 5 + k) * 6;
        o[0] = fb0; o[1] = fb1; o[2] = fb2; o[3] = 1.0f; o[4] = fa1; o[5] = fa2;
        sc[k][0] = fb0; sc[k][1] = fb1; sc[k][2] = fb2; sc[k][3] = fa1; sc[k][4] = fa2;
    }
    __syncthreads();

    // A (10x10): column i = one-sample cascade update of basis e_i with x=0.
    if (t < 10) {
        double z[10];
#pragma unroll
        for (int i = 0; i < 10; ++i) z[i] = 0.0;
        z[t] = 1.0;
        double s = 0.0;
        double zn[10];
#pragma unroll
        for (int k = 0; k < 5; ++k) {
            double b0 = sc[k][0], b1 = sc[k][1], b2 = sc[k][2];
            double a1 = sc[k][3], a2 = sc[k][4];
            double y = b0 * s + z[2 * k];
            zn[2 * k]     = b1 * s - a1 * y + z[2 * k + 1];
            zn[2 * k + 1] = b2 * s - a2 * y;
            s = y;
        }
#pragma unroll
        for (int r = 0; r < 10; ++r) Abuf[0][r][t] = zn[r];
    }
    __syncthreads();

    int r = t / 10, cc = t % 10;
    int cur = 0;
    for (int sq = 0; sq < 16; ++sq) {
        double acc = 0.0;
        if (t < 100) {
#pragma unroll
            for (int j = 0; j < 10; ++j) acc += Abuf[cur][r][j] * Abuf[cur][j][cc];
        }
        __syncthreads();
        if (t < 100) Abuf[cur ^ 1][r][cc] = acc;
        __syncthreads();
        cur ^= 1;
        if (sq >= 3 && t < 100) {
            int m = sq - 3;   // sq=3 -> A^16 = P_0 ... sq=15 -> A^65536 = P_12
            powers[((size_t)b * NPOW + m) * 100 + t] = (float)Abuf[cur][r][cc];
        }
    }
}

// ---- triangular affine: v = P*u (+v if ACC); P is a GLOBAL 10x10 matrix
// addressed wave-uniformly -> s_load / SGPR operands. Row rr uses cols
// 0..(rr|1) (block-lower-triangular, exact zeros). ----
template<bool ACC>
__device__ __forceinline__ void affineT(const float* __restrict__ P,
                                        const float u[10], float v[10])
{
#pragma unroll
    for (int rr = 0; rr < 10; ++rr) {
        const float* rp = P + rr * 10;
        float a = ACC ? v[rr] : 0.0f;
#pragma unroll
        for (int c = 0; c <= (rr | 1); ++c) a = fmaf(rp[c], u[c], a);
        v[rr] = a;
    }
}

__device__ __forceinline__ void matvecT(const float* __restrict__ P, float v[10])
{
    float u[10];
#pragma unroll
    for (int i = 0; i < 10; ++i) u[i] = v[i];
    affineT<false>(P, u, v);
}

// ---------------- K2a: pass1 — per-chunk exclusive prefixes + wave totals ---
__global__ __launch_bounds__(256, 2)
void eq_pass1(const float* __restrict__ x, const float* __restrict__ sos,
              const float* __restrict__ powers, float* __restrict__ es_g,
              float* __restrict__ wt)
{
    int blk = blockIdx.x;
    int b = blk >> 5, sp = blk & (BPB - 1);
    int tid = threadIdx.x;
    int w = tid >> 6, lw = tid & 63;

    const float* s5 = sos + (size_t)(b * 5) * 6;
    float cb0[5], cb1[5], cb2[5], ca1[5], ca2[5];
#pragma unroll
    for (int k = 0; k < 5; ++k) {
        cb0[k] = s5[k * 6 + 0]; cb1[k] = s5[k * 6 + 1]; cb2[k] = s5[k * 6 + 2];
        ca1[k] = s5[k * 6 + 4]; ca2[k] = s5[k * 6 + 5];
    }

    int c = sp * CPB + tid;
    const float* xp = x + (size_t)b * T_LEN + (size_t)c * LCH;
    float xr[LCH];
#pragma unroll
    for (int t0 = 0; t0 < LCH; t0 += 4) {
        float4 xv = *reinterpret_cast<const float4*>(xp + t0);
        xr[t0] = xv.x; xr[t0 + 1] = xv.y; xr[t0 + 2] = xv.z; xr[t0 + 3] = xv.w;
    }

    // zero-state cascade -> chunk end state
    float z1[5] = {0, 0, 0, 0, 0}, z2[5] = {0, 0, 0, 0, 0};
#pragma unroll
    for (int j = 0; j < LCH; ++j) {
        float s = xr[j];
#pragma unroll
        for (int k = 0; k < 5; ++k) {
            float yk = fmaf(cb0[k], s, z1[k]);
            float u  = fmaf(cb1[k], s, z2[k]);
            z1[k] = fmaf(-ca1[k], yk, u);
            z2[k] = fmaf(-ca2[k], yk, cb2[k] * s);
            s = yk;
        }
    }
    float sv[10];
#pragma unroll
    for (int k = 0; k < 5; ++k) { sv[2 * k] = z1[k]; sv[2 * k + 1] = z2[k]; }

    // in-wave KS scan over 64 chunks (P_0..P_5, SGPR operands)
    const float* Pb = powers + (size_t)b * NPOW * 100;
#pragma unroll
    for (int j = 0; j < 6; ++j) {
        const float* P = Pb + j * 100;
        float u[10];
#pragma unroll
        for (int i = 0; i < 10; ++i) u[i] = __shfl_up(sv[i], 1 << j);
        if (lw >= (1 << j)) affineT<true>(P, u, sv);
    }

    // exclusive in-wave prefix -> global (i-major, coalesced)
    float es[10];
#pragma unroll
    for (int i = 0; i < 10; ++i) es[i] = __shfl_up(sv[i], 1);
    if (lw == 0) {
#pragma unroll
        for (int i = 0; i < 10; ++i) es[i] = 0.0f;
    }
    float* ep = es_g + (size_t)b * 10 * CCH + c;
#pragma unroll
    for (int i = 0; i < 10; ++i) ep[(size_t)i * CCH] = es[i];

    if (lw == 63) {
        int wid = sp * 4 + w;
        float* wp = wt + (size_t)(b * WPB + wid) * 10;
#pragma unroll
        for (int i = 0; i < 10; ++i) wp[i] = sv[i];
    }
}

// ---------------- K2b: pass2 — fused scan + exact states + output ----------
__global__ __launch_bounds__(256, 2)
void eq_pass2(const float* __restrict__ x, const float* __restrict__ sos,
              const float* __restrict__ powers, const float* __restrict__ wt,
              const float* __restrict__ es_g, float* __restrict__ y)
{
    int blk = blockIdx.x;
    int b = blk >> 5, sp = blk & (BPB - 1);
    int tid = threadIdx.x;
    int w = tid >> 6, lw = tid & 63;

    __shared__ float ys[CPB * 17];          // 17.4 KB, stride-17 padded

    const float* Pb = powers + (size_t)b * NPOW * 100;
    int wid = sp * 4 + w;                   // this wave's global wave index

    // ---- in-wave redundant scan over this batch's 128 wave totals ----
    const float* wp = wt + (size_t)(b * WPB + 2 * lw) * 10;
    float t0[10], t1[10];
#pragma unroll
    for (int i = 0; i < 10; ++i) { t0[i] = wp[i]; t1[i] = wp[10 + i]; }

    float tau[10];
#pragma unroll
    for (int i = 0; i < 10; ++i) tau[i] = t1[i];
    affineT<true>(Pb + 6 * 100, t0, tau);   // pair total (2048 samples)

#pragma unroll
    for (int j = 0; j < 6; ++j) {           // KS over 64 pairs, P_(7+j)
        const float* P = Pb + (7 + j) * 100;
        float u[10];
#pragma unroll
        for (int i = 0; i < 10; ++i) u[i] = __shfl_up(tau[i], 1 << j);
        if (lw >= (1 << j)) affineT<true>(P, u, tau);
    }

    float e[10];                            // entering state of wave 2lw
#pragma unroll
    for (int i = 0; i < 10; ++i) e[i] = __shfl_up(tau[i], 1);
    if (lw == 0) {
#pragma unroll
        for (int i = 0; i < 10; ++i) e[i] = 0.0f;
    }
    float s1[10];                           // entering state of wave 2lw+1
#pragma unroll
    for (int i = 0; i < 10; ++i) s1[i] = t0[i];
    affineT<true>(Pb + 6 * 100, e, s1);

    // this wave's seed: lane (wid>>1)'s e (wid even) or s1 (wid odd)
    float F[10];
#pragma unroll
    for (int i = 0; i < 10; ++i)
        F[i] = __shfl((wid & 1) ? s1[i] : e[i], wid >> 1);

    // ---- x load ----
    int c = sp * CPB + tid;
    const float* xp = x + (size_t)b * T_LEN + (size_t)c * LCH;
    float xr[LCH];
#pragma unroll
    for (int t2 = 0; t2 < LCH; t2 += 4) {
        float4 xv = *reinterpret_cast<const float4*>(xp + t2);
        xr[t2] = xv.x; xr[t2 + 1] = xv.y; xr[t2 + 2] = xv.z; xr[t2 + 3] = xv.w;
    }

    // ---- F = A^(16*lw) * seed (powers commute), + es -> exact state ----
#pragma unroll
    for (int m = 0; m < 6; ++m) {
        if ((lw >> m) & 1) matvecT(Pb + m * 100, F);
    }

    const float* s5 = sos + (size_t)(b * 5) * 6;
    float cb0[5], cb1[5], cb2[5], ca1[5], ca2[5];
#pragma unroll
    for (int k = 0; k < 5; ++k) {
        cb0[k] = s5[k * 6 + 0]; cb1[k] = s5[k * 6 + 1]; cb2[k] = s5[k * 6 + 2];
        ca1[k] = s5[k * 6 + 4]; ca2[k] = s5[k * 6 + 5];
    }

    const float* ep = es_g + (size_t)b * 10 * CCH + c;
    float z1[5], z2[5];
#pragma unroll
    for (int k = 0; k < 5; ++k) {
        z1[k] = F[2 * k]     + ep[(size_t)(2 * k) * CCH];
        z2[k] = F[2 * k + 1] + ep[(size_t)(2 * k + 1) * CCH];
    }

    // ---- final cascade -> LDS (padded stride 17) ----
    float* yl = ys + tid * 17;
#pragma unroll
    for (int j = 0; j < LCH; ++j) {
        float s = xr[j];
#pragma unroll
        for (int k = 0; k < 5; ++k) {
            float yk = fmaf(cb0[k], s, z1[k]);
            float u  = fmaf(cb1[k], s, z2[k]);
            z1[k] = fmaf(-ca1[k], yk, u);
            z2[k] = fmaf(-ca2[k], yk, cb2[k] * s);
            s = yk;
        }
        yl[j] = s;
    }
    __syncthreads();

    // ---- coalesced copy-out: 256 threads x 4 float4 = 4096 samples ----
    float* yg = y + (size_t)b * T_LEN + (size_t)sp * (CPB * LCH);
#pragma unroll
    for (int it = 0; it < (CPB * LCH) / (256 * 4); ++it) {
        int i = (tid + it * 256) * 4;
        int p = (i >> 4) * 17 + (i & 15);
        *reinterpret_cast<float4*>(yg + i) =
            make_float4(ys[p], ys[p + 1], ys[p + 2], ys[p + 3]);
    }
}

extern "C" void kernel_launch(void* const* d_in, const int* in_sizes, int n_in,
                              void* d_out, int out_size, void* d_ws, size_t ws_size,
                              hipStream_t stream)
{
    const float* x  = (const float*)d_in[0];
    const float* cp = (const float*)d_in[1];
    float* out = (float*)d_out;
    float* sos = out + (size_t)NB * T_LEN;          // sos tail of d_out

    float* powers = (float*)d_ws;                        // NB*NPOW*100
    float* wt     = powers + (size_t)NB * NPOW * 100;    // NB*WPB*10
    float* es_g   = wt + (size_t)NB * WPB * 10;          // NB*10*CCH

    eq_setup<<<dim3(NB), dim3(128), 0, stream>>>(cp, sos, powers);
    eq_pass1<<<dim3(NB * BPB), dim3(256), 0, stream>>>(x, sos, powers, es_g, wt);
    eq_pass2<<<dim3(NB * BPB), dim3(256), 0, stream>>>(x, sos, powers, wt, es_g, out);
}

// Round 15
// 43.670 us; speedup vs baseline: 1.0564x; 1.0316x over previous
//
#include <hip/hip_runtime.h>
#include <math.h>

// ParametricEQ: 5-section cascaded biquad over (32, 131072).
// 10-state linear recurrence z' = A z + b x (A block-lower-triangular).
// Wait-free 3-kernel pipeline, LCH=32 geometry:
//   K1  setup : RBJ coeffs (fp64) + P_m = A^(32*2^m), m=0..11.
//   K2a pass1 : per 32-sample chunk zero-state cascade; in-wave KS (P0..P5);
//               store per-chunk exclusive prefix es (i-major, coalesced);
//               lane63 -> wave total (64 per batch).
//   K2b pass2 : in-wave scan of 64 wave totals (P6..P11) -> own seed (shfl);
//               F = A^(32*lw)*seed + es -> exact state; final cascade;
//               direct float4 y stores (one 128B line per thread).
// P matrices via wave-uniform global loads (s_load / SGPR operands).

#define NB 32
#define LCH 32
#define T_LEN 131072
#define CPB 256                 // chunks per block
#define BPB 16                  // blocks per batch
#define CCH 4096                // chunks per batch
#define WPB 64                  // waves per batch
#define NPOW 12

__constant__ double c_lo[15] = {-12.0,   20.0, 0.1,
                                -12.0,   20.0, 0.1,
                                -12.0,  200.0, 0.1,
                                -12.0, 2000.0, 0.1,
                                -12.0, 4000.0, 0.1};
__constant__ double c_hi[15] = { 12.0,  2000.0, 10.0,
                                 12.0,   200.0, 10.0,
                                 12.0,  2000.0, 10.0,
                                 12.0, 12000.0, 10.0,
                                 12.0, 16000.0, 10.0};

// ---------------- K1: coeffs + cascade matrix powers -----------------------
__global__ __launch_bounds__(128)
void eq_setup(const float* __restrict__ cp, float* __restrict__ sos_out,
              float* __restrict__ powers)
{
    int b = blockIdx.x;
    int t = threadIdx.x;
    __shared__ float  sc[5][5];
    __shared__ double Abuf[2][10][10];

    if (t < 5) {
        int k = t;
        double p[3];
#pragma unroll
        for (int j = 0; j < 3; ++j) {
            int i = k * 3 + j;
            double pv = (double)cp[b * 15 + i];
            p[j] = c_lo[i] + pv * (c_hi[i] - c_lo[i]);
        }
        double A     = exp(p[0] * (M_LN10 / 40.0));
        double w0    = 2.0 * M_PI * p[1] / 44100.0;
        double alpha = sin(w0) / (2.0 * p[2]);
        double cw    = cos(w0);
        double sA    = sqrt(A);
        double b0, b1, b2, a0, a1, a2;
        if (k == 0) {            // low shelf
            b0 =     A * ((A + 1) - (A - 1) * cw + 2 * sA * alpha);
            b1 = 2 * A * ((A - 1) - (A + 1) * cw);
            b2 =     A * ((A + 1) - (A - 1) * cw - 2 * sA * alpha);
            a0 =          (A + 1) + (A - 1) * cw + 2 * sA * alpha;
            a1 =    -2 * ((A - 1) + (A + 1) * cw);
            a2 =          (A + 1) + (A - 1) * cw - 2 * sA * alpha;
        } else if (k == 4) {     // high shelf
            b0 =     A * ((A + 1) + (A - 1) * cw + 2 * sA * alpha);
            b1 = -2 * A * ((A - 1) + (A + 1) * cw);
            b2 =     A * ((A + 1) + (A - 1) * cw - 2 * sA * alpha);
            a0 =          (A + 1) - (A - 1) * cw + 2 * sA * alpha;
            a1 =     2 * ((A - 1) - (A + 1) * cw);
            a2 =          (A + 1) - (A - 1) * cw - 2 * sA * alpha;
        } else {                 // peaking
            b0 = 1.0 + alpha * A;
            b1 = -2.0 * cw;
            b2 = 1.0 - alpha * A;
            a0 = 1.0 + alpha / A;
            a1 = -2.0 * cw;
            a2 = 1.0 - alpha / A;
        }
        double inv = 1.0 / a0;
        float fb0 = (float)(b0 * inv), fb1 = (float)(b1 * inv), fb2 = (float)(b2 * inv);
        float fa1 = (float)(a1 * inv), fa2 = (float)(a2 * inv);
        float* o = sos_out + (size_t)(b * 5 + k) * 6;
        o[0] = fb0; o[1] = fb1; o[2] = fb2; o[3] = 1.0f; o[4] = fa1; o[5] = fa2;
        sc[k][0] = fb0; sc[k][1] = fb1; sc[k][2] = fb2; sc[k][3] = fa1; sc[k][4] = fa2;
    }
    __syncthreads();

    // A (10x10): column i = one-sample cascade update of basis e_i with x=0.
    if (t < 10) {
        double z[10];
#pragma unroll
        for (int i = 0; i < 10; ++i) z[i] = 0.0;
        z[t] = 1.0;
        double s = 0.0;
        double zn[10];
#pragma unroll
        for (int k = 0; k < 5; ++k) {
            double b0 = sc[k][0], b1 = sc[k][1], b2 = sc[k][2];
            double a1 = sc[k][3], a2 = sc[k][4];
            double y = b0 * s + z[2 * k];
            zn[2 * k]     = b1 * s - a1 * y + z[2 * k + 1];
            zn[2 * k + 1] = b2 * s - a2 * y;
            s = y;
        }
#pragma unroll
        for (int r = 0; r < 10; ++r) Abuf[0][r][t] = zn[r];
    }
    __syncthreads();

    int r = t / 10, cc = t % 10;
    int cur = 0;
    for (int sq = 0; sq < 16; ++sq) {
        double acc = 0.0;
        if (t < 100) {
#pragma unroll
            for (int j = 0; j < 10; ++j) acc += Abuf[cur][r][j] * Abuf[cur][j][cc];
        }
        __syncthreads();
        if (t < 100) Abuf[cur ^ 1][r][cc] = acc;
        __syncthreads();
        cur ^= 1;
        if (sq >= 4 && t < 100) {
            int m = sq - 4;   // sq=4 -> A^32 = P_0 ... sq=15 -> A^65536 = P_11
            powers[((size_t)b * NPOW + m) * 100 + t] = (float)Abuf[cur][r][cc];
        }
    }
}

// ---- triangular affine: v = P*u (+v if ACC); P is a GLOBAL 10x10 matrix
// addressed wave-uniformly -> s_load / SGPR operands. Row rr uses cols
// 0..(rr|1) (block-lower-triangular, exact zeros). ----
template<bool ACC>
__device__ __forceinline__ void affineT(const float* __restrict__ P,
                                        const float u[10], float v[10])
{
#pragma unroll
    for (int rr = 0; rr < 10; ++rr) {
        const float* rp = P + rr * 10;
        float a = ACC ? v[rr] : 0.0f;
#pragma unroll
        for (int c = 0; c <= (rr | 1); ++c) a = fmaf(rp[c], u[c], a);
        v[rr] = a;
    }
}

__device__ __forceinline__ void matvecT(const float* __restrict__ P, float v[10])
{
    float u[10];
#pragma unroll
    for (int i = 0; i < 10; ++i) u[i] = v[i];
    affineT<false>(P, u, v);
}

// ---------------- K2a: pass1 — per-chunk exclusive prefixes + wave totals ---
__global__ __launch_bounds__(256, 2)
void eq_pass1(const float* __restrict__ x, const float* __restrict__ sos,
              const float* __restrict__ powers, float* __restrict__ es_g,
              float* __restrict__ wt)
{
    int blk = blockIdx.x;
    int b = blk >> 4, sp = blk & (BPB - 1);
    int tid = threadIdx.x;
    int w = tid >> 6, lw = tid & 63;

    const float* s5 = sos + (size_t)(b * 5) * 6;
    float cb0[5], cb1[5], cb2[5], ca1[5], ca2[5];
#pragma unroll
    for (int k = 0; k < 5; ++k) {
        cb0[k] = s5[k * 6 + 0]; cb1[k] = s5[k * 6 + 1]; cb2[k] = s5[k * 6 + 2];
        ca1[k] = s5[k * 6 + 4]; ca2[k] = s5[k * 6 + 5];
    }

    int c = sp * CPB + tid;
    const float* xp = x + (size_t)b * T_LEN + (size_t)c * LCH;
    float xr[LCH];
#pragma unroll
    for (int t0 = 0; t0 < LCH; t0 += 4) {
        float4 xv = *reinterpret_cast<const float4*>(xp + t0);
        xr[t0] = xv.x; xr[t0 + 1] = xv.y; xr[t0 + 2] = xv.z; xr[t0 + 3] = xv.w;
    }

    // zero-state cascade -> chunk end state
    float z1[5] = {0, 0, 0, 0, 0}, z2[5] = {0, 0, 0, 0, 0};
#pragma unroll
    for (int j = 0; j < LCH; ++j) {
        float s = xr[j];
#pragma unroll
        for (int k = 0; k < 5; ++k) {
            float yk = fmaf(cb0[k], s, z1[k]);
            float u  = fmaf(cb1[k], s, z2[k]);
            z1[k] = fmaf(-ca1[k], yk, u);
            z2[k] = fmaf(-ca2[k], yk, cb2[k] * s);
            s = yk;
        }
    }
    float sv[10];
#pragma unroll
    for (int k = 0; k < 5; ++k) { sv[2 * k] = z1[k]; sv[2 * k + 1] = z2[k]; }

    // in-wave KS scan over 64 chunks (P_0..P_5, SGPR operands)
    const float* Pb = powers + (size_t)b * NPOW * 100;
#pragma unroll
    for (int j = 0; j < 6; ++j) {
        const float* P = Pb + j * 100;
        float u[10];
#pragma unroll
        for (int i = 0; i < 10; ++i) u[i] = __shfl_up(sv[i], 1 << j);
        if (lw >= (1 << j)) affineT<true>(P, u, sv);
    }

    // exclusive in-wave prefix -> global (i-major, coalesced)
    float es[10];
#pragma unroll
    for (int i = 0; i < 10; ++i) es[i] = __shfl_up(sv[i], 1);
    if (lw == 0) {
#pragma unroll
        for (int i = 0; i < 10; ++i) es[i] = 0.0f;
    }
    float* ep = es_g + (size_t)b * 10 * CCH + c;
#pragma unroll
    for (int i = 0; i < 10; ++i) ep[(size_t)i * CCH] = es[i];

    if (lw == 63) {
        int wid = sp * 4 + w;
        float* wp = wt + (size_t)(b * WPB + wid) * 10;
#pragma unroll
        for (int i = 0; i < 10; ++i) wp[i] = sv[i];
    }
}

// ---------------- K2b: pass2 — fused scan + exact states + output ----------
__global__ __launch_bounds__(256, 2)
void eq_pass2(const float* __restrict__ x, const float* __restrict__ sos,
              const float* __restrict__ powers, const float* __restrict__ wt,
              const float* __restrict__ es_g, float* __restrict__ y)
{
    int blk = blockIdx.x;
    int b = blk >> 4, sp = blk & (BPB - 1);
    int tid = threadIdx.x;
    int w = tid >> 6, lw = tid & 63;

    const float* Pb = powers + (size_t)b * NPOW * 100;
    int wid = sp * 4 + w;                   // this wave's index in [0, 64)

    // ---- in-wave scan over this batch's 64 wave totals ----
    const float* wp = wt + (size_t)(b * WPB + lw) * 10;
    float tau[10];
#pragma unroll
    for (int i = 0; i < 10; ++i) tau[i] = wp[i];

#pragma unroll
    for (int j = 0; j < 6; ++j) {           // KS over 64, distance 1<<j uses P_(6+j)
        const float* P = Pb + (6 + j) * 100;
        float u[10];
#pragma unroll
        for (int i = 0; i < 10; ++i) u[i] = __shfl_up(tau[i], 1 << j);
        if (lw >= (1 << j)) affineT<true>(P, u, tau);
    }

    // exclusive prefix; this wave's seed = lane (wid-1)'s inclusive (0 if wid==0)
    float F[10];
#pragma unroll
    for (int i = 0; i < 10; ++i) {
        float iv = __shfl(tau[i], (wid - 1) & 63);
        F[i] = (wid == 0) ? 0.0f : iv;
    }

    // ---- x load ----
    int c = sp * CPB + tid;
    const float* xp = x + (size_t)b * T_LEN + (size_t)c * LCH;
    float xr[LCH];
#pragma unroll
    for (int t2 = 0; t2 < LCH; t2 += 4) {
        float4 xv = *reinterpret_cast<const float4*>(xp + t2);
        xr[t2] = xv.x; xr[t2 + 1] = xv.y; xr[t2 + 2] = xv.z; xr[t2 + 3] = xv.w;
    }

    // ---- F = A^(32*lw) * seed (powers commute), + es -> exact state ----
#pragma unroll
    for (int m = 0; m < 6; ++m) {
        if ((lw >> m) & 1) matvecT(Pb + m * 100, F);
    }

    const float* s5 = sos + (size_t)(b * 5) * 6;
    float cb0[5], cb1[5], cb2[5], ca1[5], ca2[5];
#pragma unroll
    for (int k = 0; k < 5; ++k) {
        cb0[k] = s5[k * 6 + 0]; cb1[k] = s5[k * 6 + 1]; cb2[k] = s5[k * 6 + 2];
        ca1[k] = s5[k * 6 + 4]; ca2[k] = s5[k * 6 + 5];
    }

    const float* ep = es_g + (size_t)b * 10 * CCH + c;
    float z1[5], z2[5];
#pragma unroll
    for (int k = 0; k < 5; ++k) {
        z1[k] = F[2 * k]     + ep[(size_t)(2 * k) * CCH];
        z2[k] = F[2 * k + 1] + ep[(size_t)(2 * k + 1) * CCH];
    }

    // ---- final cascade -> direct y stores (one 128B line per thread) ----
    float* yp = y + (size_t)b * T_LEN + (size_t)c * LCH;
#pragma unroll
    for (int t0 = 0; t0 < LCH; t0 += 4) {
        float o4[4];
#pragma unroll
        for (int j = 0; j < 4; ++j) {
            float s = xr[t0 + j];
#pragma unroll
            for (int k = 0; k < 5; ++k) {
                float yk = fmaf(cb0[k], s, z1[k]);
                float u  = fmaf(cb1[k], s, z2[k]);
                z1[k] = fmaf(-ca1[k], yk, u);
                z2[k] = fmaf(-ca2[k], yk, cb2[k] * s);
                s = yk;
            }
            o4[j] = s;
        }
        *reinterpret_cast<float4*>(yp + t0) = make_float4(o4[0], o4[1], o4[2], o4[3]);
    }
}

extern "C" void kernel_launch(void* const* d_in, const int* in_sizes, int n_in,
                              void* d_out, int out_size, void* d_ws, size_t ws_size,
                              hipStream_t stream)
{
    const float* x  = (const float*)d_in[0];
    const float* cp = (const float*)d_in[1];
    float* out = (float*)d_out;
    float* sos = out + (size_t)NB * T_LEN;          // sos tail of d_out

    float* powers = (float*)d_ws;                        // NB*NPOW*100
    float* wt     = powers + (size_t)NB * NPOW * 100;    // NB*WPB*10
    float* es_g   = wt + (size_t)NB * WPB * 10;          // NB*10*CCH

    eq_setup<<<dim3(NB), dim3(128), 0, stream>>>(cp, sos, powers);
    eq_pass1<<<dim3(NB * BPB), dim3(256), 0, stream>>>(x, sos, powers, es_g, wt);
    eq_pass2<<<dim3(NB * BPB), dim3(256), 0, stream>>>(x, sos, powers, wt, es_g, out);
}